// Round 11
// baseline (531.685 us; speedup 1.0000x reference)
//
#include <hip/hip_runtime.h>

#define DIMD 256
#define PDIM 256
#define NB   8
#define LSEQ 4096
#define MTOT (NB*LSEQ)      // 32768
#define FDIM 2560
#define NCHUNK 64
#define CLEN 64

typedef __attribute__((ext_vector_type(8))) short s8bf;   // 8 bf16 = 4 VGPRs
typedef __attribute__((ext_vector_type(4))) float f32x4;

#define MFMA16(a,b,c) __builtin_amdgcn_mfma_f32_16x16x32_bf16((a),(b),(c),0,0,0)

// ---- workspace layout (float offsets) ----
static const size_t OFF_LBR  = 0;      // lam_bar re           [256]
static const size_t OFF_LBI  = 256;    // lam_bar im
static const size_t OFF_A64R = 512;    // lam_bar^64 re
static const size_t OFF_A64I = 768;
static const size_t OFF_WR   = 1024;   // w = B_bar . l1_w
static const size_t OFF_WI   = 1280;
static const size_t OFF_CR   = 1536;   // c = B_bar . l1_b
static const size_t OFF_CI   = 1792;
static const size_t OFF_DBL2 = 2048;   // scalar: dec_b.l2w + l2b
static const size_t OFF_E_RE   = 4096;                       // chunk end states [8][64][256]
static const size_t OFF_E_IM   = OFF_E_RE   + 131072;
static const size_t OFF_CAR_RE = OFF_E_IM   + 131072;        // chunk carry-in   [8][64][256]
static const size_t OFF_CAR_IM = OFF_CAR_RE + 131072;
static const size_t OFF_H1     = OFF_CAR_IM + 131072;        // h1 bf16 [32768][256] (4,194,304 floats)
static const size_t OFF_ENC16  = OFF_H1     + 4194304;       // enc_w bf16 [2560][256]
static const size_t OFF_DL     = OFF_ENC16  + 327680;        // dl f32 [2560] = dec^T . l2w
static const size_t OFF_CC16   = OFF_DL     + 327680;        // Cc bf16 [256][512] k-interleaved
// end ~ 5.2M floats = 21 MB

__device__ __forceinline__ ushort f2bf(float f) {
    union { float f; unsigned u; } v; v.f = f;
    unsigned u = v.u;
    return (ushort)((u + 0x7FFFu + ((u >> 16) & 1u)) >> 16);   // RNE
}
__device__ __forceinline__ float bf2f(ushort h) {
    union { unsigned u; float f; } v; v.u = ((unsigned)h) << 16;
    return v.f;
}
// tanh = 1 - 2/(e^{2x}+1); rcp(inf)=0 -> +1, e^{2x}->0 -> -1: no clamps needed
__device__ __forceinline__ float fast_tanh(float x) {
    float e = __expf(2.f * x);
    return 1.f - 2.f * __builtin_amdgcn_rcpf(e + 1.f);
}

// ---- weight prep + consts + dl, one launch ----
// bid <2560: enc->bf16 ; 2560..3071: Cc16 ; 3072: per-p consts + (dec_b.l2w+l2b) ;
// 3073..3082: dl[k] = sum_n dec_w[n][k] * l2w[n]
__global__ void k_prep(const float* __restrict__ enc_w, const float* __restrict__ dec_w,
                       const float* __restrict__ C_re, const float* __restrict__ C_im,
                       const float* __restrict__ l1w, const float* __restrict__ l1b,
                       const float* __restrict__ lam_re, const float* __restrict__ lam_im,
                       const float* __restrict__ B_re, const float* __restrict__ B_im,
                       const float* __restrict__ log_step, const float* __restrict__ dec_b,
                       const float* __restrict__ l2w, const float* __restrict__ l2b,
                       ushort* __restrict__ enc16, ushort* __restrict__ cc16,
                       float* __restrict__ dlv, float* __restrict__ ws) {
    __shared__ float red[4];
    int bid = blockIdx.x, t = threadIdx.x;
    if (bid < 2560) {
        int i = bid * 256 + t;
        enc16[i] = f2bf(enc_w[i]);
    } else if (bid < 3072) {
        int j = (bid - 2560) * 256 + t;       // 512 blocks -> 131072 = 256*512
        int h = j >> 9, c = j & 511;
        int p = c >> 1;
        // Cc16[h][2p] = 2*C_re[h][p] ; Cc16[h][2p+1] = -2*C_im[h][p]  (matches xs)
        float v = ((c & 1) == 0) ? 2.f * C_re[h * 256 + p] : -2.f * C_im[h * 256 + p];
        cc16[j] = f2bf(v);
    } else if (bid == 3072) {
        int p = t;
        float st = expf(log_step[p]);
        float lr = lam_re[p], li = lam_im[p];
        float zr = lr * st, zi = li * st;
        float er = expf(zr);
        float lbr = er * cosf(zi), lbi = er * sinf(zi);
        float den = lr * lr + li * li;
        float nr = lbr - 1.0f, ni = lbi;
        float facr = (nr * lr + ni * li) / den;
        float faci = (ni * lr - nr * li) / den;
        float dwr = 0.f, dwi = 0.f, dbr = 0.f, dbi = 0.f;
        for (int h = 0; h < DIMD; ++h) {
            float br = B_re[p * DIMD + h], bi = B_im[p * DIMD + h];
            float w1 = l1w[h], b1 = l1b[h];
            dwr = fmaf(br, w1, dwr); dwi = fmaf(bi, w1, dwi);
            dbr = fmaf(br, b1, dbr); dbi = fmaf(bi, b1, dbi);
        }
        float wr = facr * dwr - faci * dwi, wi = facr * dwi + faci * dwr;
        float cr = facr * dbr - faci * dbi, ci = facr * dbi + faci * dbr;
        float ar = lbr, ai = lbi;
        for (int s = 0; s < 6; ++s) { float tq = ar * ar - ai * ai; ai = 2.f * ar * ai; ar = tq; }
        ws[OFF_LBR + p] = lbr;  ws[OFF_LBI + p] = lbi;
        ws[OFF_A64R + p] = ar;  ws[OFF_A64I + p] = ai;
        ws[OFF_WR + p] = wr;    ws[OFF_WI + p] = wi;
        ws[OFF_CR + p] = cr;    ws[OFF_CI + p] = ci;
        // scalar: dec_b . l2w + l2b
        float s = dec_b[t] * l2w[t];
        #pragma unroll
        for (int off = 1; off < 64; off <<= 1) s += __shfl_xor(s, off, 64);
        if ((t & 63) == 0) red[t >> 6] = s;
        __syncthreads();
        if (t == 0) ws[OFF_DBL2] = red[0] + red[1] + red[2] + red[3] + l2b[0];
    } else {
        int k = (bid - 3073) * 256 + t;       // 10 blocks -> 2560
        float s0 = 0.f, s1 = 0.f;
        for (int n = 0; n < 256; n += 2) {
            s0 = fmaf(dec_w[(size_t)n * FDIM + k], l2w[n], s0);
            s1 = fmaf(dec_w[(size_t)(n + 1) * FDIM + k], l2w[n + 1], s1);
        }
        dlv[k] = s0 + s1;
    }
}

// ---- scan pass A: per (b,chunk,p) chunk-local end state (zero init) ----
__global__ void k_scanA(const float* __restrict__ x, float* __restrict__ ws) {
    int p = threadIdx.x, chunk = blockIdx.x, b = blockIdx.y;
    float lbr = ws[OFF_LBR + p], lbi = ws[OFF_LBI + p];
    float wr = ws[OFF_WR + p], wi = ws[OFF_WI + p];
    float cr = ws[OFF_CR + p], ci = ws[OFF_CI + p];
    const float* xb = x + (size_t)b * LSEQ + chunk * CLEN;
    float sr = 0.f, si = 0.f;
    for (int t = 0; t < CLEN; ++t) {
        float xv = xb[t];
        float bur = fmaf(xv, wr, cr), bui = fmaf(xv, wi, ci);
        float nsr = fmaf(lbr, sr, fmaf(-lbi, si, bur));
        float nsi = fmaf(lbr, si, fmaf(lbi, sr, bui));
        sr = nsr; si = nsi;
    }
    size_t idx = ((size_t)b * NCHUNK + chunk) * PDIM + p;
    ws[OFF_E_RE + idx] = sr; ws[OFF_E_IM + idx] = si;
}

// ---- scan pass B: combine chunks, store carry-in per chunk ----
__global__ void k_scanB(float* __restrict__ ws) {
    int p = threadIdx.x, b = blockIdx.x;
    float ar = ws[OFF_A64R + p], ai = ws[OFF_A64I + p];
    float sr = 0.f, si = 0.f;
    for (int c = 0; c < NCHUNK; ++c) {
        size_t idx = ((size_t)b * NCHUNK + c) * PDIM + p;
        ws[OFF_CAR_RE + idx] = sr; ws[OFF_CAR_IM + idx] = si;
        float er = ws[OFF_E_RE + idx], ei = ws[OFF_E_IM + idx];
        float nsr = fmaf(ar, sr, fmaf(-ai, si, er));
        float nsi = fmaf(ar, si, fmaf(ai, sr, ei));
        sr = nsr; si = nsi;
    }
}

// ---- fused scanC + C-projection (bf16 MFMA) + S5 epilogue -> h1 bf16 ----
__global__ __launch_bounds__(256) void k_scg(
        const float* __restrict__ x, const float* __restrict__ ws,
        const ushort* __restrict__ cc16, const float* __restrict__ l1w,
        const float* __restrict__ l1b, const float* __restrict__ Dv,
        ushort* __restrict__ h1) {
    __shared__ ushort xs[64 * 512];   // 64 KB: row=t (1024B), col 2p=re, 2p+1=im
    __shared__ float xbuf[64];
    const int t = threadIdx.x;
    const int chunk = blockIdx.x, b = blockIdx.y;
    const size_t row0 = (size_t)b * LSEQ + chunk * CLEN;
    if (t < 64) xbuf[t] = x[row0 + t];
    const int p = t;
    float lbr = ws[OFF_LBR + p], lbi = ws[OFF_LBI + p];
    float wr = ws[OFF_WR + p], wi = ws[OFF_WI + p];
    float cr = ws[OFF_CR + p], ci = ws[OFF_CI + p];
    size_t cidx = ((size_t)b * NCHUNK + chunk) * PDIM + p;
    float sr = ws[OFF_CAR_RE + cidx], si = ws[OFF_CAR_IM + cidx];
    __syncthreads();
    for (int tt = 0; tt < CLEN; ++tt) {
        float xv = xbuf[tt];
        float bur = fmaf(xv, wr, cr), bui = fmaf(xv, wi, ci);
        float nsr = fmaf(lbr, sr, fmaf(-lbi, si, bur));
        float nsi = fmaf(lbr, si, fmaf(lbi, sr, bui));
        sr = nsr; si = nsi;
        unsigned pk;
        asm("v_cvt_pk_bf16_f32 %0, %1, %2" : "=v"(pk) : "v"(sr), "v"(si));
        *(unsigned*)((char*)xs + tt * 1024 + ((p * 4) ^ ((tt & 7) << 4))) = pk;
    }
    __syncthreads();
    // GEMM: out 64x256, K=512
    const int w = t >> 6, l = t & 63, lr = l & 15, lg = l >> 4;
    const f32x4 fz = {0.f, 0.f, 0.f, 0.f};
    f32x4 acc[4][4];
    #pragma unroll
    for (int mi = 0; mi < 4; ++mi)
        #pragma unroll
        for (int nj = 0; nj < 4; ++nj) acc[mi][nj] = fz;
    for (int ks = 0; ks < 16; ++ks) {
        s8bf a[4];
        #pragma unroll
        for (int mi = 0; mi < 4; ++mi) {
            int row = mi * 16 + lr;
            a[mi] = *(const s8bf*)((const char*)xs + row * 1024 + ((ks * 64 + lg * 16) ^ ((row & 7) << 4)));
        }
        #pragma unroll
        for (int nj = 0; nj < 4; ++nj) {
            int n = w * 64 + nj * 16 + lr;
            s8bf bfrag = *(const s8bf*)(cc16 + (size_t)n * 512 + ks * 32 + lg * 8);
            #pragma unroll
            for (int mi = 0; mi < 4; ++mi)
                acc[mi][nj] = MFMA16(a[mi], bfrag, acc[mi][nj]);
        }
    }
    // epilogue: u = x*l1w + l1b ; h1 = tanh(D*u + 2Re(Cx)) + u   (2x folded into Cc16)
    #pragma unroll
    for (int nj = 0; nj < 4; ++nj) {
        int n = w * 64 + nj * 16 + lr;
        float l1wn = l1w[n], l1bn = l1b[n], dn = Dv[n];
        #pragma unroll
        for (int mi = 0; mi < 4; ++mi)
            #pragma unroll
            for (int r = 0; r < 4; ++r) {
                int mrow = mi * 16 + lg * 4 + r;
                float u = fmaf(xbuf[mrow], l1wn, l1bn);
                float s = fmaf(dn, u, acc[mi][nj][r]);
                h1[(row0 + mrow) * DIMD + n] = f2bf(fast_tanh(s) + u);
            }
    }
}

// ---- FFN v6 (k_ff4): dl-folded, split-K(FDIM) x2 for co-residency ----
// Grid (512, 2): blockIdx.x = 64-row tile, blockIdx.y = khalf (chunks 10*khalf..+10).
// A-frags read from LDS per chunk (NOT hoisted): keeps VGPR <= 64 so 4 blocks/CU
// co-reside (r10 showed the hoisted version ran ~1 block/CU serially; r8/r9 showed
// LDS reads/conflicts aren't binding). No barriers in loop. Results atomicAdd into
// zeroed out; khalf=0 contributes residual dot + (dec_b.l2w + l2b).
__global__ __launch_bounds__(512, 8) void k_ff4(
        const ushort* __restrict__ h1g, const ushort* __restrict__ enc16,
        const float* __restrict__ enc_b, const float* __restrict__ dlv,
        const float* __restrict__ l2w, const float* __restrict__ wsc,
        float* __restrict__ out) {
    __shared__ ushort h1s[64 * 256];   // 32 KB, XOR-swizzled rows (512 B stride)
    __shared__ float osum[64];
    const int t = threadIdx.x;
    const int m0 = blockIdx.x * 64;
    const int khalf = blockIdx.y;
    const int w = t >> 6, l = t & 63;
    const int lr = l & 15, lg = l >> 4;

    #pragma unroll
    for (int e = 0; e < 4; ++e) {
        int flat = e * 512 + t;
        int row = flat >> 5, unit = flat & 31;
        s8bf v = *(const s8bf*)(h1g + (size_t)(m0 + row) * 256 + unit * 8);
        *(s8bf*)((char*)h1s + row * 512 + ((unit * 16) ^ ((row & 7) << 4))) = v;
    }
    if (t < 64) osum[t] = 0.f;
    __syncthreads();

    // ---- residual dot (khalf==0 only stores): sum_n h1[m][n]*l2w[n] + const ----
    if (khalf == 0) {
        const int m = t >> 3, j = t & 7;       // 8 threads per row
        float rs = 0.f;
        #pragma unroll
        for (int q = 0; q < 4; ++q) {
            int n = j * 32 + q * 8;
            s8bf v = *(const s8bf*)((const char*)h1s + m * 512 + ((2 * n) ^ ((m & 7) << 4)));
            #pragma unroll
            for (int e = 0; e < 8; ++e)
                rs = fmaf(bf2f((ushort)v[e]), l2w[n + e], rs);
        }
        rs += __shfl_xor(rs, 1, 8);
        rs += __shfl_xor(rs, 2, 8);
        rs += __shfl_xor(rs, 4, 8);
        if (j == 0) osum[m] = rs + wsc[OFF_DBL2];
    }
    __syncthreads();

    const f32x4 fz = {0.f, 0.f, 0.f, 0.f};
    float dacc[4][4] = {{0.f}};
    const ushort* encBase = enc16 + (size_t)(w * 16 + lr) * 256;

    const int c0 = khalf * 10;
    for (int c = c0; c < c0 + 10; ++c) {
        const int k0 = c * 128;
        const int kc = k0 + w * 16 + lr;       // this lane's f-column
        f32x4 facc[4] = {fz, fz, fz, fz};
        const ushort* encRow = encBase + (size_t)k0 * 256;
        #pragma unroll
        for (int kd = 0; kd < 8; ++kd) {
            s8bf bfrag = *(const s8bf*)(encRow + kd * 32 + lg * 8);
            #pragma unroll
            for (int mi = 0; mi < 4; ++mi) {
                int row = mi * 16 + lr;
                int kb = kd * 64 + lg * 16;
                s8bf a = *(const s8bf*)((const char*)h1s + row * 512 + (kb ^ ((row & 7) << 4)));
                facc[mi] = MFMA16(a, bfrag, facc[mi]);
            }
        }
        float ebv = enc_b[kc];
        float dlk = dlv[kc];
        #pragma unroll
        for (int mi = 0; mi < 4; ++mi)
            #pragma unroll
            for (int r = 0; r < 4; ++r)
                dacc[mi][r] = fmaf(fast_tanh(facc[mi][r] + ebv), dlk, dacc[mi][r]);
    }
    // ---- reduce dacc over the 16 lr-lanes (same m), atomic into osum ----
    #pragma unroll
    for (int mi = 0; mi < 4; ++mi)
        #pragma unroll
        for (int r = 0; r < 4; ++r) {
            float s = dacc[mi][r];
            s += __shfl_xor(s, 1, 16);
            s += __shfl_xor(s, 2, 16);
            s += __shfl_xor(s, 4, 16);
            s += __shfl_xor(s, 8, 16);
            if (lr == 0) atomicAdd(&osum[mi * 16 + 4 * lg + r], s);
        }
    __syncthreads();
    if (t < 64) atomicAdd(&out[m0 + t], osum[t]);
}

extern "C" void kernel_launch(void* const* d_in, const int* in_sizes, int n_in,
                              void* d_out, int out_size, void* d_ws, size_t ws_size,
                              hipStream_t stream) {
    const float* x       = (const float*)d_in[0];
    const float* l1w     = (const float*)d_in[1];
    const float* l1b     = (const float*)d_in[2];
    const float* lam_re  = (const float*)d_in[3];
    const float* lam_im  = (const float*)d_in[4];
    const float* B_re    = (const float*)d_in[5];
    const float* B_im    = (const float*)d_in[6];
    const float* C_re    = (const float*)d_in[7];
    const float* C_im    = (const float*)d_in[8];
    const float* Dv      = (const float*)d_in[9];
    const float* log_stp = (const float*)d_in[10];
    const float* enc_w   = (const float*)d_in[11];
    const float* enc_b   = (const float*)d_in[12];
    const float* dec_w   = (const float*)d_in[13];
    const float* dec_b   = (const float*)d_in[14];
    const float* l2w     = (const float*)d_in[15];
    const float* l2b     = (const float*)d_in[16];
    float* ws  = (float*)d_ws;
    float* out = (float*)d_out;
    ushort* h1_16 = (ushort*)(ws + OFF_H1);
    ushort* enc16 = (ushort*)(ws + OFF_ENC16);
    float*  dlv   = ws + OFF_DL;
    ushort* cc16  = (ushort*)(ws + OFF_CC16);

    hipMemsetAsync(out, 0, (size_t)MTOT * sizeof(float), stream);
    hipLaunchKernelGGL(k_prep, dim3(3083), dim3(256), 0, stream,
                       enc_w, dec_w, C_re, C_im, l1w, l1b, lam_re, lam_im,
                       B_re, B_im, log_stp, dec_b, l2w, l2b,
                       enc16, cc16, dlv, ws);
    hipLaunchKernelGGL(k_scanA, dim3(NCHUNK, NB), dim3(256), 0, stream, x, ws);
    hipLaunchKernelGGL(k_scanB, dim3(NB), dim3(256), 0, stream, ws);
    hipLaunchKernelGGL(k_scg, dim3(NCHUNK, NB), dim3(256), 0, stream,
                       x, ws, cc16, l1w, l1b, Dv, h1_16);
    hipLaunchKernelGGL(k_ff4, dim3(MTOT / 64, 2), dim3(512), 0, stream,
                       h1_16, enc16, enc_b, dlv, l2w, ws, out);
}

// Round 12
// 355.178 us; speedup vs baseline: 1.4970x; 1.4970x over previous
//
#include <hip/hip_runtime.h>

#define DIMD 256
#define PDIM 256
#define NB   8
#define LSEQ 4096
#define MTOT (NB*LSEQ)      // 32768
#define FDIM 2560
#define NCHUNK 64
#define CLEN 64

typedef __attribute__((ext_vector_type(8))) short s8bf;   // 8 bf16 = 4 VGPRs
typedef __attribute__((ext_vector_type(4))) float f32x4;

#define MFMA16(a,b,c) __builtin_amdgcn_mfma_f32_16x16x32_bf16((a),(b),(c),0,0,0)

// ---- workspace layout (float offsets) ----
static const size_t OFF_LBR  = 0;      // lam_bar re           [256]
static const size_t OFF_LBI  = 256;    // lam_bar im
static const size_t OFF_A64R = 512;    // lam_bar^64 re
static const size_t OFF_A64I = 768;
static const size_t OFF_WR   = 1024;   // w = B_bar . l1_w
static const size_t OFF_WI   = 1280;
static const size_t OFF_CR   = 1536;   // c = B_bar . l1_b
static const size_t OFF_CI   = 1792;
static const size_t OFF_DBL2 = 2048;   // scalar: dec_b.l2w + l2b
static const size_t OFF_E_RE   = 4096;                       // chunk end states [8][64][256]
static const size_t OFF_E_IM   = OFF_E_RE   + 131072;
static const size_t OFF_CAR_RE = OFF_E_IM   + 131072;        // chunk carry-in   [8][64][256]
static const size_t OFF_CAR_IM = OFF_CAR_RE + 131072;
static const size_t OFF_H1     = OFF_CAR_IM + 131072;        // h1 bf16 [32768][256] (4,194,304 floats)
static const size_t OFF_ENC16  = OFF_H1     + 4194304;       // enc_w bf16 [2560][256]
static const size_t OFF_DL     = OFF_ENC16  + 327680;        // dl f32 [2560] = dec^T . l2w
static const size_t OFF_CC16   = OFF_DL     + 327680;        // Cc bf16 [256][512] k-interleaved
// end ~ 5.2M floats = 21 MB

__device__ __forceinline__ ushort f2bf(float f) {
    union { float f; unsigned u; } v; v.f = f;
    unsigned u = v.u;
    return (ushort)((u + 0x7FFFu + ((u >> 16) & 1u)) >> 16);   // RNE
}
__device__ __forceinline__ float bf2f(ushort h) {
    union { unsigned u; float f; } v; v.u = ((unsigned)h) << 16;
    return v.f;
}
// tanh = 1 - 2/(e^{2x}+1); rcp(inf)=0 -> +1, e^{2x}->0 -> -1: no clamps needed
__device__ __forceinline__ float fast_tanh(float x) {
    float e = __expf(2.f * x);
    return 1.f - 2.f * __builtin_amdgcn_rcpf(e + 1.f);
}

// ---- weight prep + consts + dl, one launch ----
// bid <2560: enc->bf16 ; 2560..3071: Cc16 ; 3072: per-p consts + (dec_b.l2w+l2b) ;
// 3073..3082: dl[k] = sum_n dec_w[n][k] * l2w[n]
__global__ void k_prep(const float* __restrict__ enc_w, const float* __restrict__ dec_w,
                       const float* __restrict__ C_re, const float* __restrict__ C_im,
                       const float* __restrict__ l1w, const float* __restrict__ l1b,
                       const float* __restrict__ lam_re, const float* __restrict__ lam_im,
                       const float* __restrict__ B_re, const float* __restrict__ B_im,
                       const float* __restrict__ log_step, const float* __restrict__ dec_b,
                       const float* __restrict__ l2w, const float* __restrict__ l2b,
                       ushort* __restrict__ enc16, ushort* __restrict__ cc16,
                       float* __restrict__ dlv, float* __restrict__ ws) {
    __shared__ float red[4];
    int bid = blockIdx.x, t = threadIdx.x;
    if (bid < 2560) {
        int i = bid * 256 + t;
        enc16[i] = f2bf(enc_w[i]);
    } else if (bid < 3072) {
        int j = (bid - 2560) * 256 + t;       // 512 blocks -> 131072 = 256*512
        int h = j >> 9, c = j & 511;
        int p = c >> 1;
        // Cc16[h][2p] = 2*C_re[h][p] ; Cc16[h][2p+1] = -2*C_im[h][p]  (matches xs)
        float v = ((c & 1) == 0) ? 2.f * C_re[h * 256 + p] : -2.f * C_im[h * 256 + p];
        cc16[j] = f2bf(v);
    } else if (bid == 3072) {
        int p = t;
        float st = expf(log_step[p]);
        float lr = lam_re[p], li = lam_im[p];
        float zr = lr * st, zi = li * st;
        float er = expf(zr);
        float lbr = er * cosf(zi), lbi = er * sinf(zi);
        float den = lr * lr + li * li;
        float nr = lbr - 1.0f, ni = lbi;
        float facr = (nr * lr + ni * li) / den;
        float faci = (ni * lr - nr * li) / den;
        float dwr = 0.f, dwi = 0.f, dbr = 0.f, dbi = 0.f;
        for (int h = 0; h < DIMD; ++h) {
            float br = B_re[p * DIMD + h], bi = B_im[p * DIMD + h];
            float w1 = l1w[h], b1 = l1b[h];
            dwr = fmaf(br, w1, dwr); dwi = fmaf(bi, w1, dwi);
            dbr = fmaf(br, b1, dbr); dbi = fmaf(bi, b1, dbi);
        }
        float wr = facr * dwr - faci * dwi, wi = facr * dwi + faci * dwr;
        float cr = facr * dbr - faci * dbi, ci = facr * dbi + faci * dbr;
        float ar = lbr, ai = lbi;
        for (int s = 0; s < 6; ++s) { float tq = ar * ar - ai * ai; ai = 2.f * ar * ai; ar = tq; }
        ws[OFF_LBR + p] = lbr;  ws[OFF_LBI + p] = lbi;
        ws[OFF_A64R + p] = ar;  ws[OFF_A64I + p] = ai;
        ws[OFF_WR + p] = wr;    ws[OFF_WI + p] = wi;
        ws[OFF_CR + p] = cr;    ws[OFF_CI + p] = ci;
        // scalar: dec_b . l2w + l2b
        float s = dec_b[t] * l2w[t];
        #pragma unroll
        for (int off = 1; off < 64; off <<= 1) s += __shfl_xor(s, off, 64);
        if ((t & 63) == 0) red[t >> 6] = s;
        __syncthreads();
        if (t == 0) ws[OFF_DBL2] = red[0] + red[1] + red[2] + red[3] + l2b[0];
    } else {
        int k = (bid - 3073) * 256 + t;       // 10 blocks -> 2560
        float s0 = 0.f, s1 = 0.f;
        for (int n = 0; n < 256; n += 2) {
            s0 = fmaf(dec_w[(size_t)n * FDIM + k], l2w[n], s0);
            s1 = fmaf(dec_w[(size_t)(n + 1) * FDIM + k], l2w[n + 1], s1);
        }
        dlv[k] = s0 + s1;
    }
}

// ---- scan pass A: per (b,chunk,p) chunk-local end state (zero init) ----
__global__ void k_scanA(const float* __restrict__ x, float* __restrict__ ws) {
    int p = threadIdx.x, chunk = blockIdx.x, b = blockIdx.y;
    float lbr = ws[OFF_LBR + p], lbi = ws[OFF_LBI + p];
    float wr = ws[OFF_WR + p], wi = ws[OFF_WI + p];
    float cr = ws[OFF_CR + p], ci = ws[OFF_CI + p];
    const float* xb = x + (size_t)b * LSEQ + chunk * CLEN;
    float sr = 0.f, si = 0.f;
    for (int t = 0; t < CLEN; ++t) {
        float xv = xb[t];
        float bur = fmaf(xv, wr, cr), bui = fmaf(xv, wi, ci);
        float nsr = fmaf(lbr, sr, fmaf(-lbi, si, bur));
        float nsi = fmaf(lbr, si, fmaf(lbi, sr, bui));
        sr = nsr; si = nsi;
    }
    size_t idx = ((size_t)b * NCHUNK + chunk) * PDIM + p;
    ws[OFF_E_RE + idx] = sr; ws[OFF_E_IM + idx] = si;
}

// ---- scan pass B: combine chunks, store carry-in per chunk ----
__global__ void k_scanB(float* __restrict__ ws) {
    int p = threadIdx.x, b = blockIdx.x;
    float ar = ws[OFF_A64R + p], ai = ws[OFF_A64I + p];
    float sr = 0.f, si = 0.f;
    for (int c = 0; c < NCHUNK; ++c) {
        size_t idx = ((size_t)b * NCHUNK + c) * PDIM + p;
        ws[OFF_CAR_RE + idx] = sr; ws[OFF_CAR_IM + idx] = si;
        float er = ws[OFF_E_RE + idx], ei = ws[OFF_E_IM + idx];
        float nsr = fmaf(ar, sr, fmaf(-ai, si, er));
        float nsi = fmaf(ar, si, fmaf(ai, sr, ei));
        sr = nsr; si = nsi;
    }
}

// ---- fused scanC + C-projection (bf16 MFMA) + S5 epilogue -> h1 bf16 ----
__global__ __launch_bounds__(256) void k_scg(
        const float* __restrict__ x, const float* __restrict__ ws,
        const ushort* __restrict__ cc16, const float* __restrict__ l1w,
        const float* __restrict__ l1b, const float* __restrict__ Dv,
        ushort* __restrict__ h1) {
    __shared__ ushort xs[64 * 512];   // 64 KB: row=t (1024B), col 2p=re, 2p+1=im
    __shared__ float xbuf[64];
    const int t = threadIdx.x;
    const int chunk = blockIdx.x, b = blockIdx.y;
    const size_t row0 = (size_t)b * LSEQ + chunk * CLEN;
    if (t < 64) xbuf[t] = x[row0 + t];
    const int p = t;
    float lbr = ws[OFF_LBR + p], lbi = ws[OFF_LBI + p];
    float wr = ws[OFF_WR + p], wi = ws[OFF_WI + p];
    float cr = ws[OFF_CR + p], ci = ws[OFF_CI + p];
    size_t cidx = ((size_t)b * NCHUNK + chunk) * PDIM + p;
    float sr = ws[OFF_CAR_RE + cidx], si = ws[OFF_CAR_IM + cidx];
    __syncthreads();
    for (int tt = 0; tt < CLEN; ++tt) {
        float xv = xbuf[tt];
        float bur = fmaf(xv, wr, cr), bui = fmaf(xv, wi, ci);
        float nsr = fmaf(lbr, sr, fmaf(-lbi, si, bur));
        float nsi = fmaf(lbr, si, fmaf(lbi, sr, bui));
        sr = nsr; si = nsi;
        unsigned pk;
        asm("v_cvt_pk_bf16_f32 %0, %1, %2" : "=v"(pk) : "v"(sr), "v"(si));
        *(unsigned*)((char*)xs + tt * 1024 + ((p * 4) ^ ((tt & 7) << 4))) = pk;
    }
    __syncthreads();
    // GEMM: out 64x256, K=512
    const int w = t >> 6, l = t & 63, lr = l & 15, lg = l >> 4;
    const f32x4 fz = {0.f, 0.f, 0.f, 0.f};
    f32x4 acc[4][4];
    #pragma unroll
    for (int mi = 0; mi < 4; ++mi)
        #pragma unroll
        for (int nj = 0; nj < 4; ++nj) acc[mi][nj] = fz;
    for (int ks = 0; ks < 16; ++ks) {
        s8bf a[4];
        #pragma unroll
        for (int mi = 0; mi < 4; ++mi) {
            int row = mi * 16 + lr;
            a[mi] = *(const s8bf*)((const char*)xs + row * 1024 + ((ks * 64 + lg * 16) ^ ((row & 7) << 4)));
        }
        #pragma unroll
        for (int nj = 0; nj < 4; ++nj) {
            int n = w * 64 + nj * 16 + lr;
            s8bf bfrag = *(const s8bf*)(cc16 + (size_t)n * 512 + ks * 32 + lg * 8);
            #pragma unroll
            for (int mi = 0; mi < 4; ++mi)
                acc[mi][nj] = MFMA16(a[mi], bfrag, acc[mi][nj]);
        }
    }
    // epilogue: u = x*l1w + l1b ; h1 = tanh(D*u + 2Re(Cx)) + u   (2x folded into Cc16)
    #pragma unroll
    for (int nj = 0; nj < 4; ++nj) {
        int n = w * 64 + nj * 16 + lr;
        float l1wn = l1w[n], l1bn = l1b[n], dn = Dv[n];
        #pragma unroll
        for (int mi = 0; mi < 4; ++mi)
            #pragma unroll
            for (int r = 0; r < 4; ++r) {
                int mrow = mi * 16 + lg * 4 + r;
                float u = fmaf(xbuf[mrow], l1wn, l1bn);
                float s = fmaf(dn, u, acc[mi][nj][r]);
                h1[(row0 + mrow) * DIMD + n] = f2bf(fast_tanh(s) + u);
            }
    }
}

// ---- FFN v7 (k_ff5): dl-folded, split-K(FDIM) x2, launch_bounds(512,4) ----
// r11's (512,8) forced VGPR=32 -> accumulator spill to scratch (FETCH 1.1GB,
// WRITE 238MB, 415us). (512,4) = 128-VGPR budget: loop live set (~80) fits,
// no spill; 4 waves/SIMD allows 2 co-resident 8-wave blocks/CU (the r10
// deficit). Body unchanged from r11: A-frags from LDS per chunk, no barriers
// in loop, atomicAdd merge into zeroed out.
__global__ __launch_bounds__(512, 4) void k_ff5(
        const ushort* __restrict__ h1g, const ushort* __restrict__ enc16,
        const float* __restrict__ enc_b, const float* __restrict__ dlv,
        const float* __restrict__ l2w, const float* __restrict__ wsc,
        float* __restrict__ out) {
    __shared__ ushort h1s[64 * 256];   // 32 KB, XOR-swizzled rows (512 B stride)
    __shared__ float osum[64];
    const int t = threadIdx.x;
    const int m0 = blockIdx.x * 64;
    const int khalf = blockIdx.y;
    const int w = t >> 6, l = t & 63;
    const int lr = l & 15, lg = l >> 4;

    #pragma unroll
    for (int e = 0; e < 4; ++e) {
        int flat = e * 512 + t;
        int row = flat >> 5, unit = flat & 31;
        s8bf v = *(const s8bf*)(h1g + (size_t)(m0 + row) * 256 + unit * 8);
        *(s8bf*)((char*)h1s + row * 512 + ((unit * 16) ^ ((row & 7) << 4))) = v;
    }
    if (t < 64) osum[t] = 0.f;
    __syncthreads();

    // ---- residual dot (khalf==0 only): sum_n h1[m][n]*l2w[n] + const ----
    if (khalf == 0) {
        const int m = t >> 3, j = t & 7;       // 8 threads per row
        float rs = 0.f;
        #pragma unroll
        for (int q = 0; q < 4; ++q) {
            int n = j * 32 + q * 8;
            s8bf v = *(const s8bf*)((const char*)h1s + m * 512 + ((2 * n) ^ ((m & 7) << 4)));
            #pragma unroll
            for (int e = 0; e < 8; ++e)
                rs = fmaf(bf2f((ushort)v[e]), l2w[n + e], rs);
        }
        rs += __shfl_xor(rs, 1, 8);
        rs += __shfl_xor(rs, 2, 8);
        rs += __shfl_xor(rs, 4, 8);
        if (j == 0) osum[m] = rs + wsc[OFF_DBL2];
    }
    __syncthreads();

    const f32x4 fz = {0.f, 0.f, 0.f, 0.f};
    float dacc[4][4] = {{0.f}};
    const ushort* encBase = enc16 + (size_t)(w * 16 + lr) * 256;

    const int c0 = khalf * 10;
    for (int c = c0; c < c0 + 10; ++c) {
        const int k0 = c * 128;
        const int kc = k0 + w * 16 + lr;       // this lane's f-column
        f32x4 facc[4] = {fz, fz, fz, fz};
        const ushort* encRow = encBase + (size_t)k0 * 256;
        #pragma unroll
        for (int kd = 0; kd < 8; ++kd) {
            s8bf bfrag = *(const s8bf*)(encRow + kd * 32 + lg * 8);
            #pragma unroll
            for (int mi = 0; mi < 4; ++mi) {
                int row = mi * 16 + lr;
                int kb = kd * 64 + lg * 16;
                s8bf a = *(const s8bf*)((const char*)h1s + row * 512 + (kb ^ ((row & 7) << 4)));
                facc[mi] = MFMA16(a, bfrag, facc[mi]);
            }
        }
        float ebv = enc_b[kc];
        float dlk = dlv[kc];
        #pragma unroll
        for (int mi = 0; mi < 4; ++mi)
            #pragma unroll
            for (int r = 0; r < 4; ++r)
                dacc[mi][r] = fmaf(fast_tanh(facc[mi][r] + ebv), dlk, dacc[mi][r]);
    }
    // ---- reduce dacc over the 16 lr-lanes (same m), atomic into osum ----
    #pragma unroll
    for (int mi = 0; mi < 4; ++mi)
        #pragma unroll
        for (int r = 0; r < 4; ++r) {
            float s = dacc[mi][r];
            s += __shfl_xor(s, 1, 16);
            s += __shfl_xor(s, 2, 16);
            s += __shfl_xor(s, 4, 16);
            s += __shfl_xor(s, 8, 16);
            if (lr == 0) atomicAdd(&osum[mi * 16 + 4 * lg + r], s);
        }
    __syncthreads();
    if (t < 64) atomicAdd(&out[m0 + t], osum[t]);
}

extern "C" void kernel_launch(void* const* d_in, const int* in_sizes, int n_in,
                              void* d_out, int out_size, void* d_ws, size_t ws_size,
                              hipStream_t stream) {
    const float* x       = (const float*)d_in[0];
    const float* l1w     = (const float*)d_in[1];
    const float* l1b     = (const float*)d_in[2];
    const float* lam_re  = (const float*)d_in[3];
    const float* lam_im  = (const float*)d_in[4];
    const float* B_re    = (const float*)d_in[5];
    const float* B_im    = (const float*)d_in[6];
    const float* C_re    = (const float*)d_in[7];
    const float* C_im    = (const float*)d_in[8];
    const float* Dv      = (const float*)d_in[9];
    const float* log_stp = (const float*)d_in[10];
    const float* enc_w   = (const float*)d_in[11];
    const float* enc_b   = (const float*)d_in[12];
    const float* dec_w   = (const float*)d_in[13];
    const float* dec_b   = (const float*)d_in[14];
    const float* l2w     = (const float*)d_in[15];
    const float* l2b     = (const float*)d_in[16];
    float* ws  = (float*)d_ws;
    float* out = (float*)d_out;
    ushort* h1_16 = (ushort*)(ws + OFF_H1);
    ushort* enc16 = (ushort*)(ws + OFF_ENC16);
    float*  dlv   = ws + OFF_DL;
    ushort* cc16  = (ushort*)(ws + OFF_CC16);

    hipMemsetAsync(out, 0, (size_t)MTOT * sizeof(float), stream);
    hipLaunchKernelGGL(k_prep, dim3(3083), dim3(256), 0, stream,
                       enc_w, dec_w, C_re, C_im, l1w, l1b, lam_re, lam_im,
                       B_re, B_im, log_stp, dec_b, l2w, l2b,
                       enc16, cc16, dlv, ws);
    hipLaunchKernelGGL(k_scanA, dim3(NCHUNK, NB), dim3(256), 0, stream, x, ws);
    hipLaunchKernelGGL(k_scanB, dim3(NB), dim3(256), 0, stream, ws);
    hipLaunchKernelGGL(k_scg, dim3(NCHUNK, NB), dim3(256), 0, stream,
                       x, ws, cc16, l1w, l1b, Dv, h1_16);
    hipLaunchKernelGGL(k_ff5, dim3(MTOT / 64, 2), dim3(512), 0, stream,
                       h1_16, enc16, enc_b, dlv, l2w, ws, out);
}

// Round 13
// 300.710 us; speedup vs baseline: 1.7681x; 1.1811x over previous
//
#include <hip/hip_runtime.h>

#define DIMD 256
#define PDIM 256
#define NB   8
#define LSEQ 4096
#define MTOT (NB*LSEQ)      // 32768
#define FDIM 2560
#define NCHUNK 64
#define CLEN 64

typedef __attribute__((ext_vector_type(8))) short s8bf;   // 8 bf16 = 4 VGPRs
typedef __attribute__((ext_vector_type(4))) float f32x4;

#define MFMA16(a,b,c) __builtin_amdgcn_mfma_f32_16x16x32_bf16((a),(b),(c),0,0,0)

// ---- workspace layout (float offsets) ----
static const size_t OFF_LBR  = 0;      // lam_bar re           [256]
static const size_t OFF_LBI  = 256;    // lam_bar im
static const size_t OFF_A64R = 512;    // lam_bar^64 re
static const size_t OFF_A64I = 768;
static const size_t OFF_WR   = 1024;   // w = B_bar . l1_w
static const size_t OFF_WI   = 1280;
static const size_t OFF_CR   = 1536;   // c = B_bar . l1_b
static const size_t OFF_CI   = 1792;
static const size_t OFF_DBL2 = 2048;   // scalar: dec_b.l2w + l2b
static const size_t OFF_E_RE   = 4096;                       // chunk end states [8][64][256]
static const size_t OFF_E_IM   = OFF_E_RE   + 131072;
static const size_t OFF_CAR_RE = OFF_E_IM   + 131072;        // chunk carry-in   [8][64][256]
static const size_t OFF_CAR_IM = OFF_CAR_RE + 131072;
static const size_t OFF_H1     = OFF_CAR_IM + 131072;        // h1 bf16 [32768][256] (4,194,304 floats)
static const size_t OFF_ENC16  = OFF_H1     + 4194304;       // enc_w bf16 [2560][256]
static const size_t OFF_DL     = OFF_ENC16  + 327680;        // dl f32 [2560] = dec^T . l2w
static const size_t OFF_CC16   = OFF_DL     + 327680;        // Cc bf16 [256][512] k-interleaved
// end ~ 5.2M floats = 21 MB

__device__ __forceinline__ ushort f2bf(float f) {
    union { float f; unsigned u; } v; v.f = f;
    unsigned u = v.u;
    return (ushort)((u + 0x7FFFu + ((u >> 16) & 1u)) >> 16);   // RNE
}
__device__ __forceinline__ float bf2f(ushort h) {
    union { unsigned u; float f; } v; v.u = ((unsigned)h) << 16;
    return v.f;
}
// tanh = 1 - 2/(e^{2x}+1); rcp(inf)=0 -> +1, e^{2x}->0 -> -1: no clamps needed
__device__ __forceinline__ float fast_tanh(float x) {
    float e = __expf(2.f * x);
    return 1.f - 2.f * __builtin_amdgcn_rcpf(e + 1.f);
}

// ---- weight prep + consts + dl, one launch ----
// bid <2560: enc->bf16 ; 2560..3071: Cc16 ; 3072: per-p consts + (dec_b.l2w+l2b) ;
// 3073..3082: dl[k] = sum_n dec_w[n][k] * l2w[n]
__global__ void k_prep(const float* __restrict__ enc_w, const float* __restrict__ dec_w,
                       const float* __restrict__ C_re, const float* __restrict__ C_im,
                       const float* __restrict__ l1w, const float* __restrict__ l1b,
                       const float* __restrict__ lam_re, const float* __restrict__ lam_im,
                       const float* __restrict__ B_re, const float* __restrict__ B_im,
                       const float* __restrict__ log_step, const float* __restrict__ dec_b,
                       const float* __restrict__ l2w, const float* __restrict__ l2b,
                       ushort* __restrict__ enc16, ushort* __restrict__ cc16,
                       float* __restrict__ dlv, float* __restrict__ ws) {
    __shared__ float red[4];
    int bid = blockIdx.x, t = threadIdx.x;
    if (bid < 2560) {
        int i = bid * 256 + t;
        enc16[i] = f2bf(enc_w[i]);
    } else if (bid < 3072) {
        int j = (bid - 2560) * 256 + t;       // 512 blocks -> 131072 = 256*512
        int h = j >> 9, c = j & 511;
        int p = c >> 1;
        // Cc16[h][2p] = 2*C_re[h][p] ; Cc16[h][2p+1] = -2*C_im[h][p]  (matches xs)
        float v = ((c & 1) == 0) ? 2.f * C_re[h * 256 + p] : -2.f * C_im[h * 256 + p];
        cc16[j] = f2bf(v);
    } else if (bid == 3072) {
        int p = t;
        float st = expf(log_step[p]);
        float lr = lam_re[p], li = lam_im[p];
        float zr = lr * st, zi = li * st;
        float er = expf(zr);
        float lbr = er * cosf(zi), lbi = er * sinf(zi);
        float den = lr * lr + li * li;
        float nr = lbr - 1.0f, ni = lbi;
        float facr = (nr * lr + ni * li) / den;
        float faci = (ni * lr - nr * li) / den;
        float dwr = 0.f, dwi = 0.f, dbr = 0.f, dbi = 0.f;
        for (int h = 0; h < DIMD; ++h) {
            float br = B_re[p * DIMD + h], bi = B_im[p * DIMD + h];
            float w1 = l1w[h], b1 = l1b[h];
            dwr = fmaf(br, w1, dwr); dwi = fmaf(bi, w1, dwi);
            dbr = fmaf(br, b1, dbr); dbi = fmaf(bi, b1, dbi);
        }
        float wr = facr * dwr - faci * dwi, wi = facr * dwi + faci * dwr;
        float cr = facr * dbr - faci * dbi, ci = facr * dbi + faci * dbr;
        float ar = lbr, ai = lbi;
        for (int s = 0; s < 6; ++s) { float tq = ar * ar - ai * ai; ai = 2.f * ar * ai; ar = tq; }
        ws[OFF_LBR + p] = lbr;  ws[OFF_LBI + p] = lbi;
        ws[OFF_A64R + p] = ar;  ws[OFF_A64I + p] = ai;
        ws[OFF_WR + p] = wr;    ws[OFF_WI + p] = wi;
        ws[OFF_CR + p] = cr;    ws[OFF_CI + p] = ci;
        // scalar: dec_b . l2w + l2b
        float s = dec_b[t] * l2w[t];
        #pragma unroll
        for (int off = 1; off < 64; off <<= 1) s += __shfl_xor(s, off, 64);
        if ((t & 63) == 0) red[t >> 6] = s;
        __syncthreads();
        if (t == 0) ws[OFF_DBL2] = red[0] + red[1] + red[2] + red[3] + l2b[0];
    } else {
        int k = (bid - 3073) * 256 + t;       // 10 blocks -> 2560
        float s0 = 0.f, s1 = 0.f;
        for (int n = 0; n < 256; n += 2) {
            s0 = fmaf(dec_w[(size_t)n * FDIM + k], l2w[n], s0);
            s1 = fmaf(dec_w[(size_t)(n + 1) * FDIM + k], l2w[n + 1], s1);
        }
        dlv[k] = s0 + s1;
    }
}

// ---- scan pass A: per (b,chunk,p) chunk-local end state (zero init) ----
__global__ void k_scanA(const float* __restrict__ x, float* __restrict__ ws) {
    int p = threadIdx.x, chunk = blockIdx.x, b = blockIdx.y;
    float lbr = ws[OFF_LBR + p], lbi = ws[OFF_LBI + p];
    float wr = ws[OFF_WR + p], wi = ws[OFF_WI + p];
    float cr = ws[OFF_CR + p], ci = ws[OFF_CI + p];
    const float* xb = x + (size_t)b * LSEQ + chunk * CLEN;
    float sr = 0.f, si = 0.f;
    for (int t = 0; t < CLEN; ++t) {
        float xv = xb[t];
        float bur = fmaf(xv, wr, cr), bui = fmaf(xv, wi, ci);
        float nsr = fmaf(lbr, sr, fmaf(-lbi, si, bur));
        float nsi = fmaf(lbr, si, fmaf(lbi, sr, bui));
        sr = nsr; si = nsi;
    }
    size_t idx = ((size_t)b * NCHUNK + chunk) * PDIM + p;
    ws[OFF_E_RE + idx] = sr; ws[OFF_E_IM + idx] = si;
}

// ---- scan pass B: combine chunks, store carry-in per chunk ----
__global__ void k_scanB(float* __restrict__ ws) {
    int p = threadIdx.x, b = blockIdx.x;
    float ar = ws[OFF_A64R + p], ai = ws[OFF_A64I + p];
    float sr = 0.f, si = 0.f;
    for (int c = 0; c < NCHUNK; ++c) {
        size_t idx = ((size_t)b * NCHUNK + c) * PDIM + p;
        ws[OFF_CAR_RE + idx] = sr; ws[OFF_CAR_IM + idx] = si;
        float er = ws[OFF_E_RE + idx], ei = ws[OFF_E_IM + idx];
        float nsr = fmaf(ar, sr, fmaf(-ai, si, er));
        float nsi = fmaf(ar, si, fmaf(ai, sr, ei));
        sr = nsr; si = nsi;
    }
}

// ---- fused scanC + C-projection (bf16 MFMA) + S5 epilogue -> h1 bf16 ----
__global__ __launch_bounds__(256) void k_scg(
        const float* __restrict__ x, const float* __restrict__ ws,
        const ushort* __restrict__ cc16, const float* __restrict__ l1w,
        const float* __restrict__ l1b, const float* __restrict__ Dv,
        ushort* __restrict__ h1) {
    __shared__ ushort xs[64 * 512];   // 64 KB: row=t (1024B), col 2p=re, 2p+1=im
    __shared__ float xbuf[64];
    const int t = threadIdx.x;
    const int chunk = blockIdx.x, b = blockIdx.y;
    const size_t row0 = (size_t)b * LSEQ + chunk * CLEN;
    if (t < 64) xbuf[t] = x[row0 + t];
    const int p = t;
    float lbr = ws[OFF_LBR + p], lbi = ws[OFF_LBI + p];
    float wr = ws[OFF_WR + p], wi = ws[OFF_WI + p];
    float cr = ws[OFF_CR + p], ci = ws[OFF_CI + p];
    size_t cidx = ((size_t)b * NCHUNK + chunk) * PDIM + p;
    float sr = ws[OFF_CAR_RE + cidx], si = ws[OFF_CAR_IM + cidx];
    __syncthreads();
    for (int tt = 0; tt < CLEN; ++tt) {
        float xv = xbuf[tt];
        float bur = fmaf(xv, wr, cr), bui = fmaf(xv, wi, ci);
        float nsr = fmaf(lbr, sr, fmaf(-lbi, si, bur));
        float nsi = fmaf(lbr, si, fmaf(lbi, sr, bui));
        sr = nsr; si = nsi;
        unsigned pk;
        asm("v_cvt_pk_bf16_f32 %0, %1, %2" : "=v"(pk) : "v"(sr), "v"(si));
        *(unsigned*)((char*)xs + tt * 1024 + ((p * 4) ^ ((tt & 7) << 4))) = pk;
    }
    __syncthreads();
    // GEMM: out 64x256, K=512
    const int w = t >> 6, l = t & 63, lr = l & 15, lg = l >> 4;
    const f32x4 fz = {0.f, 0.f, 0.f, 0.f};
    f32x4 acc[4][4];
    #pragma unroll
    for (int mi = 0; mi < 4; ++mi)
        #pragma unroll
        for (int nj = 0; nj < 4; ++nj) acc[mi][nj] = fz;
    for (int ks = 0; ks < 16; ++ks) {
        s8bf a[4];
        #pragma unroll
        for (int mi = 0; mi < 4; ++mi) {
            int row = mi * 16 + lr;
            a[mi] = *(const s8bf*)((const char*)xs + row * 1024 + ((ks * 64 + lg * 16) ^ ((row & 7) << 4)));
        }
        #pragma unroll
        for (int nj = 0; nj < 4; ++nj) {
            int n = w * 64 + nj * 16 + lr;
            s8bf bfrag = *(const s8bf*)(cc16 + (size_t)n * 512 + ks * 32 + lg * 8);
            #pragma unroll
            for (int mi = 0; mi < 4; ++mi)
                acc[mi][nj] = MFMA16(a[mi], bfrag, acc[mi][nj]);
        }
    }
    // epilogue: u = x*l1w + l1b ; h1 = tanh(D*u + 2Re(Cx)) + u   (2x folded into Cc16)
    #pragma unroll
    for (int nj = 0; nj < 4; ++nj) {
        int n = w * 64 + nj * 16 + lr;
        float l1wn = l1w[n], l1bn = l1b[n], dn = Dv[n];
        #pragma unroll
        for (int mi = 0; mi < 4; ++mi)
            #pragma unroll
            for (int r = 0; r < 4; ++r) {
                int mrow = mi * 16 + lg * 4 + r;
                float u = fmaf(xbuf[mrow], l1wn, l1bn);
                float s = fmaf(dn, u, acc[mi][nj][r]);
                h1[(row0 + mrow) * DIMD + n] = f2bf(fast_tanh(s) + u);
            }
    }
}

// ---- FFN v8 (k_ff6): M=32 tiles, 4-wave blocks, 4x A-frag reuse ----
// Each wave owns 64 f-cols (4 groups of 16); per kd: 2 LDS a-reads feed 8 MFMA
// (0.25 LDS/MFMA vs r10's 1.0 -- LDS issue was ~2.4x MFMA issue per CU).
// 4-wave blocks + ~90-reg live set -> multiple blocks/CU co-reside (r10 ran
// ~1x8-wave block). NO launch_bounds min-waves arg: r11/r12 proved capping the
// allocator spills the MFMA accumulators (unified VGPR/AGPR budget on gfx950).
// Full-K per block -> direct store, no memset/atomics on out.
__global__ __launch_bounds__(256) void k_ff6(
        const ushort* __restrict__ h1g, const ushort* __restrict__ enc16,
        const float* __restrict__ enc_b, const float* __restrict__ dlv,
        const float* __restrict__ l2w, const float* __restrict__ wsc,
        float* __restrict__ out) {
    __shared__ ushort h1s[32 * 256];   // 16 KB, XOR-swizzled rows (512 B stride)
    __shared__ float osum[32];
    const int t = threadIdx.x;
    const int m0 = blockIdx.x * 32;
    const int w = t >> 6, l = t & 63;
    const int lr = l & 15, lg = l >> 4;

    #pragma unroll
    for (int e = 0; e < 4; ++e) {
        int flat = e * 256 + t;                // 1024 units x 16B = 16 KB
        int row = flat >> 5, unit = flat & 31;
        s8bf v = *(const s8bf*)(h1g + (size_t)(m0 + row) * 256 + unit * 8);
        *(s8bf*)((char*)h1s + row * 512 + ((unit * 16) ^ ((row & 7) << 4))) = v;
    }
    __syncthreads();

    // ---- residual dot: osum[m] = sum_n h1[m][n]*l2w[n] + (dec_b.l2w + l2b) ----
    {
        const int m = t >> 3, j = t & 7;       // 8 threads per row, m in 0..31
        float rs = 0.f;
        #pragma unroll
        for (int q = 0; q < 4; ++q) {
            int n = j * 32 + q * 8;
            s8bf v = *(const s8bf*)((const char*)h1s + m * 512 + ((2 * n) ^ ((m & 7) << 4)));
            #pragma unroll
            for (int e = 0; e < 8; ++e)
                rs = fmaf(bf2f((ushort)v[e]), l2w[n + e], rs);
        }
        rs += __shfl_xor(rs, 1, 8);
        rs += __shfl_xor(rs, 2, 8);
        rs += __shfl_xor(rs, 4, 8);
        if (j == 0) osum[m] = rs + wsc[OFF_DBL2];
    }
    __syncthreads();    // osum init visible before atomicAdds

    const f32x4 fz = {0.f, 0.f, 0.f, 0.f};
    float dacc[2][4] = {{0.f}};
    // wave w owns f-cols w*64 + g*16 + lr, g=0..3, within each 256-wide chunk
    const ushort* encBase = enc16 + (size_t)(w * 64 + lr) * 256;

    for (int c = 0; c < 10; ++c) {
        const int k0 = c * 256;
        const size_t cOff = (size_t)k0 * 256;
        f32x4 facc[2][4];
        #pragma unroll
        for (int mi = 0; mi < 2; ++mi)
            #pragma unroll
            for (int g = 0; g < 4; ++g) facc[mi][g] = fz;
        #pragma unroll
        for (int kd = 0; kd < 8; ++kd) {
            const int kb = kd * 64 + lg * 16;
            s8bf a0 = *(const s8bf*)((const char*)h1s + lr * 512 + (kb ^ ((lr & 7) << 4)));
            int row1 = 16 + lr;
            s8bf a1 = *(const s8bf*)((const char*)h1s + row1 * 512 + (kb ^ ((row1 & 7) << 4)));
            #pragma unroll
            for (int g = 0; g < 4; ++g) {
                s8bf bfrag = *(const s8bf*)(encBase + cOff + (size_t)g * 16 * 256 + kd * 32 + lg * 8);
                facc[0][g] = MFMA16(a0, bfrag, facc[0][g]);
                facc[1][g] = MFMA16(a1, bfrag, facc[1][g]);
            }
        }
        #pragma unroll
        for (int g = 0; g < 4; ++g) {
            const int kc = k0 + w * 64 + g * 16 + lr;
            float ebv = enc_b[kc];
            float dlk = dlv[kc];
            #pragma unroll
            for (int mi = 0; mi < 2; ++mi)
                #pragma unroll
                for (int r = 0; r < 4; ++r)
                    dacc[mi][r] = fmaf(fast_tanh(facc[mi][g][r] + ebv), dlk, dacc[mi][r]);
        }
    }
    // ---- reduce dacc over the 16 lr-lanes (cols), atomic into osum (4 waves) ----
    #pragma unroll
    for (int mi = 0; mi < 2; ++mi)
        #pragma unroll
        for (int r = 0; r < 4; ++r) {
            float s = dacc[mi][r];
            s += __shfl_xor(s, 1, 16);
            s += __shfl_xor(s, 2, 16);
            s += __shfl_xor(s, 4, 16);
            s += __shfl_xor(s, 8, 16);
            if (lr == 0) atomicAdd(&osum[mi * 16 + 4 * lg + r], s);
        }
    __syncthreads();
    if (t < 32) out[m0 + t] = osum[t];
}

extern "C" void kernel_launch(void* const* d_in, const int* in_sizes, int n_in,
                              void* d_out, int out_size, void* d_ws, size_t ws_size,
                              hipStream_t stream) {
    const float* x       = (const float*)d_in[0];
    const float* l1w     = (const float*)d_in[1];
    const float* l1b     = (const float*)d_in[2];
    const float* lam_re  = (const float*)d_in[3];
    const float* lam_im  = (const float*)d_in[4];
    const float* B_re    = (const float*)d_in[5];
    const float* B_im    = (const float*)d_in[6];
    const float* C_re    = (const float*)d_in[7];
    const float* C_im    = (const float*)d_in[8];
    const float* Dv      = (const float*)d_in[9];
    const float* log_stp = (const float*)d_in[10];
    const float* enc_w   = (const float*)d_in[11];
    const float* enc_b   = (const float*)d_in[12];
    const float* dec_w   = (const float*)d_in[13];
    const float* dec_b   = (const float*)d_in[14];
    const float* l2w     = (const float*)d_in[15];
    const float* l2b     = (const float*)d_in[16];
    float* ws  = (float*)d_ws;
    float* out = (float*)d_out;
    ushort* h1_16 = (ushort*)(ws + OFF_H1);
    ushort* enc16 = (ushort*)(ws + OFF_ENC16);
    float*  dlv   = ws + OFF_DL;
    ushort* cc16  = (ushort*)(ws + OFF_CC16);

    hipLaunchKernelGGL(k_prep, dim3(3083), dim3(256), 0, stream,
                       enc_w, dec_w, C_re, C_im, l1w, l1b, lam_re, lam_im,
                       B_re, B_im, log_stp, dec_b, l2w, l2b,
                       enc16, cc16, dlv, ws);
    hipLaunchKernelGGL(k_scanA, dim3(NCHUNK, NB), dim3(256), 0, stream, x, ws);
    hipLaunchKernelGGL(k_scanB, dim3(NB), dim3(256), 0, stream, ws);
    hipLaunchKernelGGL(k_scg, dim3(NCHUNK, NB), dim3(256), 0, stream,
                       x, ws, cc16, l1w, l1b, Dv, h1_16);
    hipLaunchKernelGGL(k_ff6, dim3(MTOT / 32), dim3(256), 0, stream,
                       h1_16, enc16, enc_b, dlv, l2w, ws, out);
}

// Round 15
// 295.617 us; speedup vs baseline: 1.7986x; 1.0172x over previous
//
#include <hip/hip_runtime.h>

#define DIMD 256
#define PDIM 256
#define NB   8
#define LSEQ 4096
#define MTOT (NB*LSEQ)      // 32768
#define FDIM 2560
#define NCHUNK 64
#define CLEN 64

typedef __attribute__((ext_vector_type(8))) short s8bf;   // 8 bf16 = 4 VGPRs
typedef __attribute__((ext_vector_type(4))) float f32x4;

#define MFMA16(a,b,c) __builtin_amdgcn_mfma_f32_16x16x32_bf16((a),(b),(c),0,0,0)

// ---- workspace layout (float offsets) ----
static const size_t OFF_LBR  = 0;      // lam_bar re           [256]
static const size_t OFF_LBI  = 256;    // lam_bar im
static const size_t OFF_A64R = 512;    // lam_bar^64 re
static const size_t OFF_A64I = 768;
static const size_t OFF_WR   = 1024;   // w = B_bar . l1_w
static const size_t OFF_WI   = 1280;
static const size_t OFF_CR   = 1536;   // c = B_bar . l1_b
static const size_t OFF_CI   = 1792;
static const size_t OFF_DBL2 = 2048;   // scalar: dec_b.l2w + l2b
static const size_t OFF_E_RE   = 4096;                       // chunk end states [8][64][256]
static const size_t OFF_E_IM   = OFF_E_RE   + 131072;
static const size_t OFF_ENC16F = OFF_E_IM   + 131072;        // enc bf16 FRAGMENT-ORDER [655360] (327680 f)
static const size_t OFF_DL     = OFF_ENC16F + 327680;        // dl f32 [2560] = dec^T . l2w
static const size_t OFF_CC16F  = OFF_DL     + 2560;          // Cc bf16 FRAGMENT-ORDER [131072] (65536 f)
// end ~ 0.66M floats = 2.6 MB

__device__ __forceinline__ ushort f2bf(float f) {
    union { float f; unsigned u; } v; v.f = f;
    unsigned u = v.u;
    return (ushort)((u + 0x7FFFu + ((u >> 16) & 1u)) >> 16);   // RNE
}
__device__ __forceinline__ float bf2f(ushort h) {
    union { unsigned u; float f; } v; v.u = ((unsigned)h) << 16;
    return v.f;
}
// tanh = 1 - 2/(e^{2x}+1); rcp(inf)=0 -> +1, e^{2x}->0 -> -1: no clamps needed
__device__ __forceinline__ float fast_tanh(float x) {
    float e = __expf(2.f * x);
    return 1.f - 2.f * __builtin_amdgcn_rcpf(e + 1.f);
}

// ---- weight prep + consts + dl, one launch ----
// FRAGMENT-ORDER pre-swizzle: a wave's MFMA B-load becomes lane l -> base + l*16B
// (one contiguous 1KB transaction instead of 16 scattered 64B lines).
// enc16f element j: e=j&7, lr=(j>>3)&15, lg=(j>>7)&3, kd=(j>>9)&7, ft=j>>12;
//   value = enc_w[(ft*16+lr)*256 + kd*32+lg*8+e]
// cc16f element j: e=j&7, lr=(j>>3)&15, lg=(j>>7)&3, ks=(j>>9)&15, nt=j>>13;
//   k = ks*32+lg*8+e (re/im interleaved): even -> 2*C_re[n][k/2], odd -> -2*C_im[n][k/2], n=nt*16+lr
__global__ void k_prep(const float* __restrict__ enc_w, const float* __restrict__ dec_w,
                       const float* __restrict__ C_re, const float* __restrict__ C_im,
                       const float* __restrict__ l1w, const float* __restrict__ l1b,
                       const float* __restrict__ lam_re, const float* __restrict__ lam_im,
                       const float* __restrict__ B_re, const float* __restrict__ B_im,
                       const float* __restrict__ log_step, const float* __restrict__ dec_b,
                       const float* __restrict__ l2w, const float* __restrict__ l2b,
                       ushort* __restrict__ enc16f, ushort* __restrict__ cc16f,
                       float* __restrict__ dlv, float* __restrict__ ws) {
    __shared__ float red[4];
    int bid = blockIdx.x, t = threadIdx.x;
    if (bid < 2560) {
        int j = bid * 256 + t;                 // 655360 elements
        int e = j & 7, lr = (j >> 3) & 15, lg = (j >> 7) & 3, kd = (j >> 9) & 7, ft = j >> 12;
        enc16f[j] = f2bf(enc_w[(size_t)(ft * 16 + lr) * 256 + kd * 32 + lg * 8 + e]);
    } else if (bid < 3072) {
        int j = (bid - 2560) * 256 + t;        // 131072 elements
        int e = j & 7, lr = (j >> 3) & 15, lg = (j >> 7) & 3, ks = (j >> 9) & 15, nt = j >> 13;
        int h = nt * 16 + lr;
        int c = ks * 32 + lg * 8 + e;
        int p = c >> 1;
        float v = ((c & 1) == 0) ? 2.f * C_re[h * 256 + p] : -2.f * C_im[h * 256 + p];
        cc16f[j] = f2bf(v);
    } else if (bid == 3072) {
        int p = t;
        float st = expf(log_step[p]);
        float lr = lam_re[p], li = lam_im[p];
        float zr = lr * st, zi = li * st;
        float er = expf(zr);
        float lbr = er * cosf(zi), lbi = er * sinf(zi);
        float den = lr * lr + li * li;
        float nr = lbr - 1.0f, ni = lbi;
        float facr = (nr * lr + ni * li) / den;
        float faci = (ni * lr - nr * li) / den;
        float dwr = 0.f, dwi = 0.f, dbr = 0.f, dbi = 0.f;
        for (int h = 0; h < DIMD; ++h) {
            float br = B_re[p * DIMD + h], bi = B_im[p * DIMD + h];
            float w1 = l1w[h], b1 = l1b[h];
            dwr = fmaf(br, w1, dwr); dwi = fmaf(bi, w1, dwi);
            dbr = fmaf(br, b1, dbr); dbi = fmaf(bi, b1, dbi);
        }
        float wr = facr * dwr - faci * dwi, wi = facr * dwi + faci * dwr;
        float cr = facr * dbr - faci * dbi, ci = facr * dbi + faci * dbr;
        float ar = lbr, ai = lbi;
        for (int s = 0; s < 6; ++s) { float tq = ar * ar - ai * ai; ai = 2.f * ar * ai; ar = tq; }
        ws[OFF_LBR + p] = lbr;  ws[OFF_LBI + p] = lbi;
        ws[OFF_A64R + p] = ar;  ws[OFF_A64I + p] = ai;
        ws[OFF_WR + p] = wr;    ws[OFF_WI + p] = wi;
        ws[OFF_CR + p] = cr;    ws[OFF_CI + p] = ci;
        float s = dec_b[t] * l2w[t];
        #pragma unroll
        for (int off = 1; off < 64; off <<= 1) s += __shfl_xor(s, off, 64);
        if ((t & 63) == 0) red[t >> 6] = s;
        __syncthreads();
        if (t == 0) ws[OFF_DBL2] = red[0] + red[1] + red[2] + red[3] + l2b[0];
    } else {
        int k = (bid - 3073) * 256 + t;       // 10 blocks -> 2560
        float s0 = 0.f, s1 = 0.f;
        for (int n = 0; n < 256; n += 2) {
            s0 = fmaf(dec_w[(size_t)n * FDIM + k], l2w[n], s0);
            s1 = fmaf(dec_w[(size_t)(n + 1) * FDIM + k], l2w[n + 1], s1);
        }
        dlv[k] = s0 + s1;
    }
}

// ---- scan pass A: per (b,chunk,p) chunk-local end state (zero init) ----
__global__ void k_scanA(const float* __restrict__ x, float* __restrict__ ws) {
    int p = threadIdx.x, chunk = blockIdx.x, b = blockIdx.y;
    float lbr = ws[OFF_LBR + p], lbi = ws[OFF_LBI + p];
    float wr = ws[OFF_WR + p], wi = ws[OFF_WI + p];
    float cr = ws[OFF_CR + p], ci = ws[OFF_CI + p];
    const float* xb = x + (size_t)b * LSEQ + chunk * CLEN;
    float sr = 0.f, si = 0.f;
    for (int t = 0; t < CLEN; ++t) {
        float xv = xb[t];
        float bur = fmaf(xv, wr, cr), bui = fmaf(xv, wi, ci);
        float nsr = fmaf(lbr, sr, fmaf(-lbi, si, bur));
        float nsi = fmaf(lbr, si, fmaf(lbi, sr, bui));
        sr = nsr; si = nsi;
    }
    size_t idx = ((size_t)b * NCHUNK + chunk) * PDIM + p;
    ws[OFF_E_RE + idx] = sr; ws[OFF_E_IM + idx] = si;
}

// ---- MEGA kernel: carry + scan + C-GEMM + S5 epilogue + FFN, h1 never leaves LDS ----
// Block = (chunk, b): 256 threads (4 waves), 64 rows. Phases:
//  0 carry: replay E-prefix (<=63 FMA) -- replaces k_scanB
//  1 scan 64 steps -> xs LDS (bf16, re/im interleaved, XOR-swizzled)
//  2 C-GEMM vs cc16f (fragment-order, coalesced 1KB B-loads) -> acc[4][4]
//  3 epilogue -> h1 bf16 into LDS (reuses xs space; barrier-fenced)
//  4 residual dot -> osum   [r14 BUG FIXED: 4 threads/row covers all 64 rows]
//  5 FFN: f=tanh(h1 enc^T+eb), dacc += f*dl (enc16f fragment-order loads)
//  6 reduce -> out. No h1/fs global traffic; 3 launches total in the graph.
__global__ __launch_bounds__(256) void k_scf(
        const float* __restrict__ x, const float* __restrict__ ws,
        const ushort* __restrict__ cc16f, const ushort* __restrict__ enc16f,
        const float* __restrict__ l1w, const float* __restrict__ l1b,
        const float* __restrict__ Dv, const float* __restrict__ enc_b,
        const float* __restrict__ dlv, const float* __restrict__ l2w,
        float* __restrict__ out) {
    __shared__ ushort xs[64 * 512];   // 64 KB; rows 1024B. First 32KB reused as h1s in phase >=3
    __shared__ float xbuf[64];
    __shared__ float osum[64];
    const int t = threadIdx.x;
    const int chunk = blockIdx.x, b = blockIdx.y;
    const size_t row0 = (size_t)b * LSEQ + chunk * CLEN;
    if (t < 64) xbuf[t] = x[row0 + t];
    const int p = t;
    // ---- phase 0: carry = prefix over E chunks (scanB folded in) ----
    float a64r = ws[OFF_A64R + p], a64i = ws[OFF_A64I + p];
    float sr = 0.f, si = 0.f;
    for (int c = 0; c < chunk; ++c) {
        size_t idx = ((size_t)b * NCHUNK + c) * PDIM + p;
        float er = ws[OFF_E_RE + idx], ei = ws[OFF_E_IM + idx];
        float nsr = fmaf(a64r, sr, fmaf(-a64i, si, er));
        float nsi = fmaf(a64r, si, fmaf(a64i, sr, ei));
        sr = nsr; si = nsi;
    }
    float lbr = ws[OFF_LBR + p], lbi = ws[OFF_LBI + p];
    float wr = ws[OFF_WR + p], wi = ws[OFF_WI + p];
    float cr = ws[OFF_CR + p], ci = ws[OFF_CI + p];
    __syncthreads();                      // xbuf ready
    // ---- phase 1: scan -> xs ----
    for (int tt = 0; tt < CLEN; ++tt) {
        float xv = xbuf[tt];
        float bur = fmaf(xv, wr, cr), bui = fmaf(xv, wi, ci);
        float nsr = fmaf(lbr, sr, fmaf(-lbi, si, bur));
        float nsi = fmaf(lbr, si, fmaf(lbi, sr, bui));
        sr = nsr; si = nsi;
        unsigned pk;
        asm("v_cvt_pk_bf16_f32 %0, %1, %2" : "=v"(pk) : "v"(sr), "v"(si));
        *(unsigned*)((char*)xs + tt * 1024 + ((p * 4) ^ ((tt & 7) << 4))) = pk;
    }
    __syncthreads();
    // ---- phase 2: C-GEMM, out 64x256, K=512 ----
    const int w = t >> 6, l = t & 63, lr = l & 15, lg = l >> 4;
    const f32x4 fz = {0.f, 0.f, 0.f, 0.f};
    f32x4 acc[4][4];
    #pragma unroll
    for (int mi = 0; mi < 4; ++mi)
        #pragma unroll
        for (int nj = 0; nj < 4; ++nj) acc[mi][nj] = fz;
    for (int ks = 0; ks < 16; ++ks) {
        s8bf a[4];
        #pragma unroll
        for (int mi = 0; mi < 4; ++mi) {
            int row = mi * 16 + lr;
            a[mi] = *(const s8bf*)((const char*)xs + row * 1024 + ((ks * 64 + lg * 16) ^ ((row & 7) << 4)));
        }
        #pragma unroll
        for (int nj = 0; nj < 4; ++nj) {
            int nt = w * 4 + nj;
            s8bf bfrag = *(const s8bf*)(cc16f + ((size_t)((nt * 16 + ks) * 4 + lg) * 16 + lr) * 8);
            #pragma unroll
            for (int mi = 0; mi < 4; ++mi)
                acc[mi][nj] = MFMA16(a[mi], bfrag, acc[mi][nj]);
        }
    }
    __syncthreads();                      // all waves done reading xs
    // ---- phase 3: h1 = tanh(D*u + 2Re(Cx)) + u -> LDS (k_ff swizzle), reuse xs ----
    char* h1s = (char*)xs;
    #pragma unroll
    for (int nj = 0; nj < 4; ++nj) {
        int n = w * 64 + nj * 16 + lr;
        float l1wn = l1w[n], l1bn = l1b[n], dn = Dv[n];
        #pragma unroll
        for (int mi = 0; mi < 4; ++mi)
            #pragma unroll
            for (int r = 0; r < 4; ++r) {
                int mrow = mi * 16 + lg * 4 + r;
                float u = fmaf(xbuf[mrow], l1wn, l1bn);
                float s = fmaf(dn, u, acc[mi][nj][r]);
                *(ushort*)(h1s + mrow * 512 + ((2 * n) ^ ((mrow & 7) << 4))) = f2bf(fast_tanh(s) + u);
            }
    }
    __syncthreads();                      // h1s complete
    // ---- phase 4: osum[m] = sum_n h1[m][n]*l2w[n] + (dec_b.l2w + l2b) ----
    {
        const int m = t >> 2, j = t & 3;       // 4 threads per row, m in 0..63
        float rs = 0.f;
        #pragma unroll
        for (int q = 0; q < 8; ++q) {
            int n = j * 64 + q * 8;
            s8bf v = *(const s8bf*)(h1s + m * 512 + ((2 * n) ^ ((m & 7) << 4)));
            #pragma unroll
            for (int e = 0; e < 8; ++e)
                rs = fmaf(bf2f((ushort)v[e]), l2w[n + e], rs);
        }
        rs += __shfl_xor(rs, 1, 4);
        rs += __shfl_xor(rs, 2, 4);
        if (j == 0) osum[m] = rs + ws[OFF_DBL2];
    }
    __syncthreads();                      // osum init visible before atomics
    // ---- phase 5: FFN, wave w owns f-cols c*256 + w*64 + g*16 + lr ----
    float dacc[4][4] = {{0.f}};
    for (int c = 0; c < 10; ++c) {
        f32x4 facc[4][4];
        #pragma unroll
        for (int g = 0; g < 4; ++g)
            #pragma unroll
            for (int mi = 0; mi < 4; ++mi) facc[g][mi] = fz;
        #pragma unroll
        for (int kd = 0; kd < 8; ++kd) {
            s8bf a[4];
            #pragma unroll
            for (int mi = 0; mi < 4; ++mi) {
                int row = mi * 16 + lr;
                a[mi] = *(const s8bf*)(h1s + row * 512 + ((kd * 64 + lg * 16) ^ ((row & 7) << 4)));
            }
            #pragma unroll
            for (int g = 0; g < 4; ++g) {
                int ft = c * 16 + w * 4 + g;
                s8bf bfrag = *(const s8bf*)(enc16f + ((size_t)((ft * 8 + kd) * 4 + lg) * 16 + lr) * 8);
                #pragma unroll
                for (int mi = 0; mi < 4; ++mi)
                    facc[g][mi] = MFMA16(a[mi], bfrag, facc[g][mi]);
            }
        }
        #pragma unroll
        for (int g = 0; g < 4; ++g) {
            int kc = c * 256 + w * 64 + g * 16 + lr;
            float ebv = enc_b[kc];
            float dlk = dlv[kc];
            #pragma unroll
            for (int mi = 0; mi < 4; ++mi)
                #pragma unroll
                for (int r = 0; r < 4; ++r)
                    dacc[mi][r] = fmaf(fast_tanh(facc[g][mi][r] + ebv), dlk, dacc[mi][r]);
        }
    }
    // ---- phase 6: reduce over 16 lr-lanes, merge, store ----
    #pragma unroll
    for (int mi = 0; mi < 4; ++mi)
        #pragma unroll
        for (int r = 0; r < 4; ++r) {
            float s = dacc[mi][r];
            s += __shfl_xor(s, 1, 16);
            s += __shfl_xor(s, 2, 16);
            s += __shfl_xor(s, 4, 16);
            s += __shfl_xor(s, 8, 16);
            if (lr == 0) atomicAdd(&osum[mi * 16 + 4 * lg + r], s);
        }
    __syncthreads();
    if (t < 64) out[row0 + t] = osum[t];
}

extern "C" void kernel_launch(void* const* d_in, const int* in_sizes, int n_in,
                              void* d_out, int out_size, void* d_ws, size_t ws_size,
                              hipStream_t stream) {
    const float* x       = (const float*)d_in[0];
    const float* l1w     = (const float*)d_in[1];
    const float* l1b     = (const float*)d_in[2];
    const float* lam_re  = (const float*)d_in[3];
    const float* lam_im  = (const float*)d_in[4];
    const float* B_re    = (const float*)d_in[5];
    const float* B_im    = (const float*)d_in[6];
    const float* C_re    = (const float*)d_in[7];
    const float* C_im    = (const float*)d_in[8];
    const float* Dv      = (const float*)d_in[9];
    const float* log_stp = (const float*)d_in[10];
    const float* enc_w   = (const float*)d_in[11];
    const float* enc_b   = (const float*)d_in[12];
    const float* dec_w   = (const float*)d_in[13];
    const float* dec_b   = (const float*)d_in[14];
    const float* l2w     = (const float*)d_in[15];
    const float* l2b     = (const float*)d_in[16];
    float* ws  = (float*)d_ws;
    float* out = (float*)d_out;
    ushort* enc16f = (ushort*)(ws + OFF_ENC16F);
    float*  dlv    = ws + OFF_DL;
    ushort* cc16f  = (ushort*)(ws + OFF_CC16F);

    hipLaunchKernelGGL(k_prep, dim3(3083), dim3(256), 0, stream,
                       enc_w, dec_w, C_re, C_im, l1w, l1b, lam_re, lam_im,
                       B_re, B_im, log_stp, dec_b, l2w, l2b,
                       enc16f, cc16f, dlv, ws);
    hipLaunchKernelGGL(k_scanA, dim3(NCHUNK, NB), dim3(256), 0, stream, x, ws);
    hipLaunchKernelGGL(k_scf, dim3(NCHUNK, NB), dim3(256), 0, stream,
                       x, ws, cc16f, enc16f, l1w, l1b, Dv, enc_b, dlv, l2w, out);
}